// Round 2
// baseline (1295.976 us; speedup 1.0000x reference)
//
#include <hip/hip_runtime.h>

#define DM 768
#define DS 16
#define SEQ 2048
#define BATCH 2
#define MROWS (BATCH*SEQ)   // 4096
#define N_UV (2*DM)         // 1536
#define N_BC (DM*DS)        // 12288

typedef _Float16 half8 __attribute__((ext_vector_type(8)));
typedef float floatx4 __attribute__((ext_vector_type(4)));

static __device__ __forceinline__ unsigned short f2h(float f) {
  _Float16 h = (_Float16)f;
  return __builtin_bit_cast(unsigned short, h);
}
static __device__ __forceinline__ float h2f(unsigned short u) {
  return (float)__builtin_bit_cast(_Float16, u);
}
static __device__ __forceinline__ float softplus_f(float x) {
  return (x > 20.f) ? x : log1pf(__expf(x));
}

// elementwise fp32 -> fp16 ; n divisible by 1024
__global__ void convert_f2h(const float* __restrict__ in,
                            unsigned short* __restrict__ out, int n) {
  int i = (blockIdx.x * blockDim.x + threadIdx.x) * 4;
  if (i >= n) return;
  float4 f = *(const float4*)(in + i);
  ushort4 h;
  h.x = f2h(f.x); h.y = f2h(f.y); h.z = f2h(f.z); h.w = f2h(f.w);
  *(ushort4*)(out + i) = h;
}

// W [K][N] fp32  ->  WT [N][K] fp16  (LDS 32x32 tile transpose, scalar access)
__global__ void transpose_f2h(const float* __restrict__ W,
                              unsigned short* __restrict__ WT, int K, int N) {
  __shared__ float tile[32][33];
  int n0 = blockIdx.x * 32, k0 = blockIdx.y * 32;
  int tx = threadIdx.x, ty = threadIdx.y;
#pragma unroll
  for (int i = 0; i < 32; i += 8)
    tile[ty + i][tx] = W[(size_t)(k0 + ty + i) * N + (n0 + tx)];
  __syncthreads();
#pragma unroll
  for (int i = 0; i < 32; i += 8)
    WT[(size_t)(n0 + ty + i) * K + (k0 + tx)] = f2h(tile[tx][ty + i]);
}

// C[M][N] = A[g(M)][K] @ BT[N][K]^T + bias ; ACT=1 -> softplus ; OUTH=1 -> fp16 out
// A-row remap: g(m) = (m/TCa)*bstride + row0 + (m%TCa); output rows stay compact.
// 128x128 tile, BK=32, 4 waves each 64x64 via 4x4 of 16x16x32 MFMA.
template<int ACT, int OUTH>
__global__ __launch_bounds__(256)
void gemm_f16(const unsigned short* __restrict__ A,
              const unsigned short* __restrict__ BT,
              const float* __restrict__ bias,
              void* __restrict__ Cout,
              int M, int N, int K, int TCa, int bstride, int row0) {
  __shared__ __align__(16) unsigned short As[128][40];  // 80B rows: 16B-multiple stride
  __shared__ __align__(16) unsigned short Bs[128][40];
  const int m0 = blockIdx.y * 128, n0 = blockIdx.x * 128;
  const int tid = threadIdx.x;
  const int lane = tid & 63, wave = tid >> 6;
  const int wm = (wave >> 1) * 64, wn = (wave & 1) * 64;
  const int l16 = lane & 15, quad = lane >> 4;
  const int sr = tid >> 2, sc = (tid & 3) * 8;

  floatx4 acc[4][4] = {};

  const int mA0 = m0 + sr, mA1 = m0 + sr + 64;
  const int gA0 = (mA0 / TCa) * bstride + row0 + (mA0 % TCa);
  const int gA1 = (mA1 / TCa) * bstride + row0 + (mA1 % TCa);
  const unsigned short* Arow0 = A + (size_t)gA0 * K + sc;
  const unsigned short* Arow1 = A + (size_t)gA1 * K + sc;
  const unsigned short* Brow0 = BT + (size_t)(n0 + sr) * K + sc;
  const unsigned short* Brow1 = BT + (size_t)(n0 + sr + 64) * K + sc;

  for (int k0 = 0; k0 < K; k0 += 32) {
    *(uint4*)&As[sr][sc]      = *(const uint4*)(Arow0 + k0);
    *(uint4*)&As[sr + 64][sc] = *(const uint4*)(Arow1 + k0);
    *(uint4*)&Bs[sr][sc]      = *(const uint4*)(Brow0 + k0);
    *(uint4*)&Bs[sr + 64][sc] = *(const uint4*)(Brow1 + k0);
    __syncthreads();
    half8 af[4], bf[4];
#pragma unroll
    for (int i = 0; i < 4; i++) {
      af[i] = __builtin_bit_cast(half8, *(const uint4*)&As[wm + i * 16 + l16][quad * 8]);
      bf[i] = __builtin_bit_cast(half8, *(const uint4*)&Bs[wn + i * 16 + l16][quad * 8]);
    }
#pragma unroll
    for (int mi = 0; mi < 4; mi++)
#pragma unroll
      for (int ni = 0; ni < 4; ni++)
        acc[mi][ni] = __builtin_amdgcn_mfma_f32_16x16x32_f16(af[mi], bf[ni], acc[mi][ni], 0, 0, 0);
    __syncthreads();
  }

  // C/D layout: col = lane&15, row = (lane>>4)*4 + reg   [m89/m91-verified]
#pragma unroll
  for (int ni = 0; ni < 4; ni++) {
    int col = n0 + wn + ni * 16 + l16;
    float bv = bias[col];
#pragma unroll
    for (int mi = 0; mi < 4; mi++) {
#pragma unroll
      for (int r = 0; r < 4; r++) {
        int row = m0 + wm + mi * 16 + quad * 4 + r;
        float v = acc[mi][ni][r] + bv;
        if (ACT == 1) v = softplus_f(v);
        if (OUTH) ((unsigned short*)Cout)[(size_t)row * N + col] = f2h(v);
        else      ((float*)Cout)[(size_t)row * N + col] = v;
      }
    }
  }
}

// depthwise causal conv K=4 over u (= uv[:, :768]); output u_conv fp16
__global__ void dwconv(const unsigned short* __restrict__ uv,
                       const float* __restrict__ Wconv,   // [768][4]
                       const float* __restrict__ bconv,
                       unsigned short* __restrict__ uc) {
  int idx = blockIdx.x * 256 + threadIdx.x;   // one per (row, c)
  int c = idx % DM;
  int row = idx / DM;
  int t = row & (SEQ - 1);
  float acc = bconv[c];
  const float* w = Wconv + c * 4;
#pragma unroll
  for (int k = 0; k < 4; k++) {
    int tt = t - 3 + k;
    if (tt >= 0)
      acc += h2f(uv[(size_t)(row - 3 + k) * N_UV + c]) * w[k];
  }
  uc[(size_t)row * DM + c] = f2h(acc);
}

// selective scan over one time-chunk: 1 wave = 4 channels x 16 states
// (lane = ch*16 + j). Carries state s in s_state between chunks.
// s_t = s*exp(dt*A) + dt*B*u ; y = sum_j C*s + D*u ; gate sigmoid(v); write fp16.
__global__ __launch_bounds__(64)
void scan_chunk(const unsigned short* __restrict__ dt,   // fp16 [MROWS][DM]
                const unsigned short* __restrict__ uc,
                const unsigned short* __restrict__ Btc,  // [BATCH*TC][N_BC]
                const unsigned short* __restrict__ Ctc,
                const unsigned short* __restrict__ uv,
                const float* __restrict__ A_log,
                const float* __restrict__ Dv,
                unsigned short* __restrict__ yg,
                float* __restrict__ s_state,             // [BATCH][N_BC]
                int ci, int TC) {
  int wid = blockIdx.x;               // 0..383
  int b = wid / (DM / 4);
  int c0 = (wid % (DM / 4)) * 4;
  int lane = threadIdx.x;
  int j = lane & 15;
  int c = c0 + (lane >> 4);
  float Acj = -__expf(A_log[c0 * DS + lane]);   // A_log[c][j], contiguous over lane
  float Dc = Dv[c];
  int col = c0 * DS + lane;
  int sidx = b * N_BC + col;
  float s = (ci == 0) ? 0.f : s_state[sidx];
  size_t gbase = (size_t)b * SEQ + (size_t)ci * TC;   // global row base
  size_t lbase = (size_t)b * TC;                      // chunk-local row base

  float n_dt[8], n_u[8], n_B[8], n_C[8], n_v[8];
#pragma unroll
  for (int i = 0; i < 8; i++) {
    size_t gr = gbase + i, lr = lbase + i;
    n_dt[i] = h2f(dt[gr * DM + c]);
    n_u[i] = h2f(uc[gr * DM + c]);
    n_B[i] = h2f(Btc[lr * N_BC + col]);
    n_C[i] = h2f(Ctc[lr * N_BC + col]);
    n_v[i] = h2f(uv[gr * N_UV + DM + c]);
  }
  for (int t0 = 0; t0 < TC; t0 += 8) {
    float c_dt[8], c_u[8], c_B[8], c_C[8], c_v[8];
#pragma unroll
    for (int i = 0; i < 8; i++) {
      c_dt[i] = n_dt[i]; c_u[i] = n_u[i]; c_B[i] = n_B[i];
      c_C[i] = n_C[i]; c_v[i] = n_v[i];
    }
    if (t0 + 8 < TC) {   // prefetch next 8 steps while computing these
#pragma unroll
      for (int i = 0; i < 8; i++) {
        size_t gr = gbase + t0 + 8 + i, lr = lbase + t0 + 8 + i;
        n_dt[i] = h2f(dt[gr * DM + c]);
        n_u[i] = h2f(uc[gr * DM + c]);
        n_B[i] = h2f(Btc[lr * N_BC + col]);
        n_C[i] = h2f(Ctc[lr * N_BC + col]);
        n_v[i] = h2f(uv[gr * N_UV + DM + c]);
      }
    }
#pragma unroll
    for (int i = 0; i < 8; i++) {
      float dtc = c_dt[i];
      float a = __expf(dtc * Acj);
      s = fmaf(s, a, dtc * c_B[i] * c_u[i]);
      float yt = c_C[i] * s;
      yt += __shfl_xor(yt, 8, 64);
      yt += __shfl_xor(yt, 4, 64);
      yt += __shfl_xor(yt, 2, 64);
      yt += __shfl_xor(yt, 1, 64);
      if (j == 0) {
        float y = yt + Dc * c_u[i];
        float g = 1.f / (1.f + __expf(-c_v[i]));
        yg[(gbase + t0 + i) * DM + c] = f2h(y * g);
      }
    }
  }
  s_state[sidx] = s;
}

extern "C" void kernel_launch(void* const* d_in, const int* in_sizes, int n_in,
                              void* d_out, int out_size, void* d_ws, size_t ws_size,
                              hipStream_t stream) {
  const float* x     = (const float*)d_in[0];
  const float* Wi    = (const float*)d_in[1];
  const float* bi    = (const float*)d_in[2];
  const float* Wconv = (const float*)d_in[3];
  const float* bconv = (const float*)d_in[4];
  const float* Wdt   = (const float*)d_in[5];
  const float* bdt   = (const float*)d_in[6];
  const float* WB    = (const float*)d_in[7];
  const float* bB    = (const float*)d_in[8];
  const float* WC    = (const float*)d_in[9];
  const float* bC    = (const float*)d_in[10];
  const float* A_log = (const float*)d_in[11];
  const float* Dv    = (const float*)d_in[12];
  const float* Wo    = (const float*)d_in[13];
  const float* bo    = (const float*)d_in[14];
  float* out = (float*)d_out;
  (void)in_sizes; (void)n_in; (void)out_size;

  auto pad = [](size_t b) { return (b + 255) & ~(size_t)255; };

  // fixed-footprint buffers
  const size_t sz_xb   = pad((size_t)MROWS * DM * 2);      // also reused as yg
  const size_t sz_WiT  = pad((size_t)N_UV * DM * 2);
  const size_t sz_WdtT = pad((size_t)DM * DM * 2);
  const size_t sz_WBT  = pad((size_t)N_BC * DM * 2);
  const size_t sz_WCT  = pad((size_t)N_BC * DM * 2);
  const size_t sz_WoT  = pad((size_t)DM * DM * 2);
  const size_t sz_uvb  = pad((size_t)MROWS * N_UV * 2);
  const size_t sz_ucb  = pad((size_t)MROWS * DM * 2);
  const size_t sz_dtb  = pad((size_t)MROWS * DM * 2);
  const size_t sz_st   = pad((size_t)BATCH * N_BC * 4);
  const size_t fixed = sz_xb + sz_WiT + sz_WdtT + sz_WBT + sz_WCT + sz_WoT +
                       sz_uvb + sz_ucb + sz_dtb + sz_st;

  // choose smallest chunk count whose footprint fits ws_size (deterministic)
  int NC = 16;
  for (int nc : {1, 2, 4, 8, 16}) {
    size_t need = fixed + 2 * pad((size_t)BATCH * (SEQ / nc) * N_BC * 2);
    if (need <= ws_size) { NC = nc; break; }
  }
  const int TC = SEQ / NC;
  const int MC = BATCH * TC;           // rows per chunk GEMM (>=256, %128==0)

  char* ws = (char*)d_ws;
  size_t off = 0;
  auto alloc = [&](size_t bytes) { char* p = ws + off; off += bytes; return p; };
  unsigned short* xb   = (unsigned short*)alloc(sz_xb);   // reused as yg
  unsigned short* WiT  = (unsigned short*)alloc(sz_WiT);
  unsigned short* WdtT = (unsigned short*)alloc(sz_WdtT);
  unsigned short* WBT  = (unsigned short*)alloc(sz_WBT);
  unsigned short* WCT  = (unsigned short*)alloc(sz_WCT);
  unsigned short* WoT  = (unsigned short*)alloc(sz_WoT);
  unsigned short* uvb  = (unsigned short*)alloc(sz_uvb);
  unsigned short* ucb  = (unsigned short*)alloc(sz_ucb);
  unsigned short* dtb  = (unsigned short*)alloc(sz_dtb);
  float*          sst  = (float*)alloc(sz_st);
  unsigned short* Btc  = (unsigned short*)alloc(pad((size_t)MC * N_BC * 2));
  unsigned short* Ctc  = (unsigned short*)alloc(pad((size_t)MC * N_BC * 2));
  unsigned short* ygb  = xb;   // x fp16 is dead after the uv GEMM

  // dtype conversions / weight transposes
  convert_f2h<<<dim3(MROWS * DM / 1024), dim3(256), 0, stream>>>(x, xb, MROWS * DM);
  transpose_f2h<<<dim3(N_UV / 32, DM / 32), dim3(32, 8), 0, stream>>>(Wi, WiT, DM, N_UV);
  transpose_f2h<<<dim3(DM / 32, DM / 32), dim3(32, 8), 0, stream>>>(Wdt, WdtT, DM, DM);
  transpose_f2h<<<dim3(N_BC / 32, DM / 32), dim3(32, 8), 0, stream>>>(WB, WBT, DM, N_BC);
  transpose_f2h<<<dim3(N_BC / 32, DM / 32), dim3(32, 8), 0, stream>>>(WC, WCT, DM, N_BC);
  transpose_f2h<<<dim3(DM / 32, DM / 32), dim3(32, 8), 0, stream>>>(Wo, WoT, DM, DM);

  // uv = x @ Wi + bi   (fp16 out)
  gemm_f16<0, 1><<<dim3(N_UV / 128, MROWS / 128), 256, 0, stream>>>(
      xb, WiT, bi, uvb, MROWS, N_UV, DM, MROWS, 0, 0);
  // u_conv
  dwconv<<<dim3(MROWS * DM / 256), 256, 0, stream>>>(uvb, Wconv, bconv, ucb);
  // dt = softplus(u_conv @ Wdt + bdt)  (fp16 out, fused softplus)
  gemm_f16<1, 1><<<dim3(DM / 128, MROWS / 128), 256, 0, stream>>>(
      ucb, WdtT, bdt, dtb, MROWS, DM, DM, MROWS, 0, 0);

  // chunked: Bt/Ct GEMMs for a time-slice, then scan that slice
  for (int ci = 0; ci < NC; ci++) {
    gemm_f16<0, 1><<<dim3(N_BC / 128, MC / 128), 256, 0, stream>>>(
        ucb, WBT, bB, Btc, MC, N_BC, DM, TC, SEQ, ci * TC);
    gemm_f16<0, 1><<<dim3(N_BC / 128, MC / 128), 256, 0, stream>>>(
        ucb, WCT, bC, Ctc, MC, N_BC, DM, TC, SEQ, ci * TC);
    scan_chunk<<<dim3(BATCH * DM / 4), 64, 0, stream>>>(
        dtb, ucb, Btc, Ctc, uvb, A_log, Dv, ygb, sst, ci, TC);
  }

  // out = yg @ Wo + bo  (fp32)
  gemm_f16<0, 0><<<dim3(DM / 128, MROWS / 128), 256, 0, stream>>>(
      ygb, WoT, bo, out, MROWS, DM, DM, MROWS, 0, 0);
}

// Round 3
// 655.834 us; speedup vs baseline: 1.9761x; 1.9761x over previous
//
#include <hip/hip_runtime.h>

#define DM 768
#define DS 16
#define SEQ 2048
#define BATCH 2
#define MROWS (BATCH*SEQ)   // 4096
#define N_UV (2*DM)         // 1536
#define N_BC (DM*DS)        // 12288
#define NGRP (BATCH*DM/4)   // 384 scan wave-groups
#define SUB 16              // time-parallel sub-chunks per NC-chunk

typedef _Float16 half8 __attribute__((ext_vector_type(8)));
typedef float floatx4 __attribute__((ext_vector_type(4)));

static __device__ __forceinline__ unsigned short f2h(float f) {
  _Float16 h = (_Float16)f;
  return __builtin_bit_cast(unsigned short, h);
}
static __device__ __forceinline__ float h2f(unsigned short u) {
  return (float)__builtin_bit_cast(_Float16, u);
}
static __device__ __forceinline__ float softplus_f(float x) {
  return (x > 20.f) ? x : log1pf(__expf(x));
}
// async global->LDS, 16B per lane; LDS dest = l + lane*16 (l must be wave-uniform)
static __device__ __forceinline__ void async_cp16(const unsigned short* g,
                                                  unsigned short* l) {
  __builtin_amdgcn_global_load_lds(
      (const __attribute__((address_space(1))) void*)g,
      (__attribute__((address_space(3))) void*)l, 16, 0, 0);
}

// elementwise fp32 -> fp16 ; n divisible by 1024
__global__ void convert_f2h(const float* __restrict__ in,
                            unsigned short* __restrict__ out, int n) {
  int i = (blockIdx.x * blockDim.x + threadIdx.x) * 4;
  if (i >= n) return;
  float4 f = *(const float4*)(in + i);
  ushort4 h;
  h.x = f2h(f.x); h.y = f2h(f.y); h.z = f2h(f.z); h.w = f2h(f.w);
  *(ushort4*)(out + i) = h;
}

// W [K][N] fp32  ->  WT [N][K] fp16  (LDS 32x32 tile transpose)
__global__ void transpose_f2h(const float* __restrict__ W,
                              unsigned short* __restrict__ WT, int K, int N) {
  __shared__ float tile[32][33];
  int n0 = blockIdx.x * 32, k0 = blockIdx.y * 32;
  int tx = threadIdx.x, ty = threadIdx.y;
#pragma unroll
  for (int i = 0; i < 32; i += 8)
    tile[ty + i][tx] = W[(size_t)(k0 + ty + i) * N + (n0 + tx)];
  __syncthreads();
#pragma unroll
  for (int i = 0; i < 32; i += 8)
    WT[(size_t)(n0 + ty + i) * K + (k0 + tx)] = f2h(tile[tx][ty + i]);
}

// C[M][N] = A[g(M)][K] @ BT[N][K]^T + bias ; ACT=1 -> softplus ; OUTH=1 -> fp16 out
// A-row remap: g(m) = (m/TCa)*bstride + row0 + (m%TCa); output rows stay compact.
// 128x128 tile, BK=32, global_load_lds width-16 staging (m97 structure),
// unpadded [128][32] LDS (global_load_lds needs base+lane*16 contiguity).
template<int ACT, int OUTH>
__global__ __launch_bounds__(256)
void gemm_f16(const unsigned short* __restrict__ A,
              const unsigned short* __restrict__ BT,
              const float* __restrict__ bias,
              void* __restrict__ Cout,
              int M, int N, int K, int TCa, int bstride, int row0) {
  __shared__ __align__(16) unsigned short As[128 * 32];
  __shared__ __align__(16) unsigned short Bs[128 * 32];
  const int m0 = blockIdx.y * 128, n0 = blockIdx.x * 128;
  const int tid = threadIdx.x;
  const int lane = tid & 63, wave = tid >> 6;
  const int wm = (wave >> 1) * 64, wn = (wave & 1) * 64;
  const int l16 = lane & 15, quad = lane >> 4;
  const int sr = tid >> 2;            // staging row 0..63 (= wave*16 + lane/4)
  const int sc = (tid & 3) * 8;       // staging col segment (elements)

  floatx4 acc[4][4] = {};

  const int mA0 = m0 + sr, mA1 = m0 + sr + 64;
  const int gA0 = (mA0 / TCa) * bstride + row0 + (mA0 % TCa);
  const int gA1 = (mA1 / TCa) * bstride + row0 + (mA1 % TCa);
  const unsigned short* Arow0 = A + (size_t)gA0 * K + sc;
  const unsigned short* Arow1 = A + (size_t)gA1 * K + sc;
  const unsigned short* Brow0 = BT + (size_t)(n0 + sr) * K + sc;
  const unsigned short* Brow1 = BT + (size_t)(n0 + sr + 64) * K + sc;
  // wave-uniform LDS bases for the 4 staged 1KB blocks this wave writes
  unsigned short* ldsA0 = As + (wave * 16) * 32;
  unsigned short* ldsA1 = As + (64 + wave * 16) * 32;
  unsigned short* ldsB0 = Bs + (wave * 16) * 32;
  unsigned short* ldsB1 = Bs + (64 + wave * 16) * 32;

  for (int k0 = 0; k0 < K; k0 += 32) {
    async_cp16(Arow0 + k0, ldsA0);
    async_cp16(Arow1 + k0, ldsA1);
    async_cp16(Brow0 + k0, ldsB0);
    async_cp16(Brow1 + k0, ldsB1);
    __syncthreads();   // drains vmcnt (global_load_lds) before use
    half8 af[4], bf[4];
#pragma unroll
    for (int i = 0; i < 4; i++) {
      af[i] = __builtin_bit_cast(half8, *(const uint4*)&As[(wm + i * 16 + l16) * 32 + quad * 8]);
      bf[i] = __builtin_bit_cast(half8, *(const uint4*)&Bs[(wn + i * 16 + l16) * 32 + quad * 8]);
    }
#pragma unroll
    for (int mi = 0; mi < 4; mi++)
#pragma unroll
      for (int ni = 0; ni < 4; ni++)
        acc[mi][ni] = __builtin_amdgcn_mfma_f32_16x16x32_f16(af[mi], bf[ni], acc[mi][ni], 0, 0, 0);
    __syncthreads();
  }

  // C/D layout: col = lane&15, row = (lane>>4)*4 + reg   [m89/m91-verified]
#pragma unroll
  for (int ni = 0; ni < 4; ni++) {
    int col = n0 + wn + ni * 16 + l16;
    float bv = bias[col];
#pragma unroll
    for (int mi = 0; mi < 4; mi++) {
#pragma unroll
      for (int r = 0; r < 4; r++) {
        int row = m0 + wm + mi * 16 + quad * 4 + r;
        float v = acc[mi][ni][r] + bv;
        if (ACT == 1) v = softplus_f(v);
        if (OUTH) ((unsigned short*)Cout)[(size_t)row * N + col] = f2h(v);
        else      ((float*)Cout)[(size_t)row * N + col] = v;
      }
    }
  }
}

// depthwise causal conv K=4 over u (= uv[:, :768]); output u_conv fp16
__global__ void dwconv(const unsigned short* __restrict__ uv,
                       const float* __restrict__ Wconv,   // [768][4]
                       const float* __restrict__ bconv,
                       unsigned short* __restrict__ uc) {
  int idx = blockIdx.x * 256 + threadIdx.x;   // one per (row, c)
  int c = idx % DM;
  int row = idx / DM;
  int t = row & (SEQ - 1);
  float acc = bconv[c];
  const float* w = Wconv + c * 4;
#pragma unroll
  for (int k = 0; k < 4; k++) {
    int tt = t - 3 + k;
    if (tt >= 0)
      acc += h2f(uv[(size_t)(row - 3 + k) * N_UV + c]) * w[k];
  }
  uc[(size_t)row * DM + c] = f2h(acc);
}

// ---- time-parallel scan over one NC-chunk ----
// lane = ch*16 + j over 4 channels; grid (NGRP, SUB); TSUB = TC/SUB steps/wave.
// Pass 1: run recurrence from s=0, record final state S and transition exp(A*sum_dt).
__global__ __launch_bounds__(64)
void scan_pass1(const unsigned short* __restrict__ dt,   // fp16 [MROWS][DM]
                const unsigned short* __restrict__ uc,
                const unsigned short* __restrict__ Btc,  // [BATCH*TC][N_BC]
                const float* __restrict__ A_log,
                float* __restrict__ Ssub,                // [SUB][BATCH][N_BC]
                float* __restrict__ Aexp,
                int ci, int TC) {
  const int TSUB = TC / SUB;
  int wid = blockIdx.x, sub = blockIdx.y;
  int b = wid / (DM / 4);
  int c0 = (wid % (DM / 4)) * 4;
  int lane = threadIdx.x;
  int c = c0 + (lane >> 4);
  float Acj = -__expf(A_log[c0 * DS + lane]);
  int col = c0 * DS + lane;
  size_t gbase = (size_t)b * SEQ + (size_t)ci * TC + (size_t)sub * TSUB;
  size_t lbase = (size_t)b * TC + (size_t)sub * TSUB;

  float s = 0.f, dsum = 0.f;
  float n_dt[8], n_u[8], n_B[8];
#pragma unroll
  for (int i = 0; i < 8; i++) {
    n_dt[i] = h2f(dt[(gbase + i) * DM + c]);
    n_u[i]  = h2f(uc[(gbase + i) * DM + c]);
    n_B[i]  = h2f(Btc[(lbase + i) * N_BC + col]);
  }
  for (int t0 = 0; t0 < TSUB; t0 += 8) {
    float c_dt[8], c_u[8], c_B[8];
#pragma unroll
    for (int i = 0; i < 8; i++) { c_dt[i] = n_dt[i]; c_u[i] = n_u[i]; c_B[i] = n_B[i]; }
    if (t0 + 8 < TSUB) {
#pragma unroll
      for (int i = 0; i < 8; i++) {
        size_t gr = gbase + t0 + 8 + i, lr = lbase + t0 + 8 + i;
        n_dt[i] = h2f(dt[gr * DM + c]);
        n_u[i]  = h2f(uc[gr * DM + c]);
        n_B[i]  = h2f(Btc[lr * N_BC + col]);
      }
    }
#pragma unroll
    for (int i = 0; i < 8; i++) {
      float dtc = c_dt[i];
      dsum += dtc;
      float a = __expf(dtc * Acj);
      s = fmaf(s, a, dtc * c_B[i] * c_u[i]);
    }
  }
  int idx = (sub * BATCH + b) * N_BC + col;
  Ssub[idx] = s;
  Aexp[idx] = __expf(Acj * dsum);
}

// chain the SUB sub-chunk transitions; carry s_state across NC-chunks
__global__ __launch_bounds__(64)
void scan_combine(const float* __restrict__ Ssub, const float* __restrict__ Aexp,
                  float* __restrict__ Sinit, float* __restrict__ s_state, int ci) {
  int wid = blockIdx.x;
  int b = wid / (DM / 4);
  int c0 = (wid % (DM / 4)) * 4;
  int col = c0 * DS + threadIdx.x;
  int sidx = b * N_BC + col;
  float s = (ci == 0) ? 0.f : s_state[sidx];
#pragma unroll
  for (int k = 0; k < SUB; k++) {
    int idx = (k * BATCH + b) * N_BC + col;
    Sinit[idx] = s;
    s = fmaf(s, Aexp[idx], Ssub[idx]);
  }
  s_state[sidx] = s;
}

// Pass 2: rerun recurrence from Sinit, emit gated output yg (fp16)
__global__ __launch_bounds__(64)
void scan_pass2(const unsigned short* __restrict__ dt,
                const unsigned short* __restrict__ uc,
                const unsigned short* __restrict__ Btc,
                const unsigned short* __restrict__ Ctc,
                const unsigned short* __restrict__ uv,
                const float* __restrict__ A_log,
                const float* __restrict__ Dv,
                const float* __restrict__ Sinit,
                unsigned short* __restrict__ yg,
                int ci, int TC) {
  const int TSUB = TC / SUB;
  int wid = blockIdx.x, sub = blockIdx.y;
  int b = wid / (DM / 4);
  int c0 = (wid % (DM / 4)) * 4;
  int lane = threadIdx.x;
  int j = lane & 15;
  int c = c0 + (lane >> 4);
  float Acj = -__expf(A_log[c0 * DS + lane]);
  float Dc = Dv[c];
  int col = c0 * DS + lane;
  float s = Sinit[(sub * BATCH + b) * N_BC + col];
  size_t gbase = (size_t)b * SEQ + (size_t)ci * TC + (size_t)sub * TSUB;
  size_t lbase = (size_t)b * TC + (size_t)sub * TSUB;

  float n_dt[8], n_u[8], n_B[8], n_C[8], n_v[8];
#pragma unroll
  for (int i = 0; i < 8; i++) {
    size_t gr = gbase + i, lr = lbase + i;
    n_dt[i] = h2f(dt[gr * DM + c]);
    n_u[i]  = h2f(uc[gr * DM + c]);
    n_B[i]  = h2f(Btc[lr * N_BC + col]);
    n_C[i]  = h2f(Ctc[lr * N_BC + col]);
    n_v[i]  = h2f(uv[gr * N_UV + DM + c]);
  }
  for (int t0 = 0; t0 < TSUB; t0 += 8) {
    float c_dt[8], c_u[8], c_B[8], c_C[8], c_v[8];
#pragma unroll
    for (int i = 0; i < 8; i++) {
      c_dt[i] = n_dt[i]; c_u[i] = n_u[i]; c_B[i] = n_B[i];
      c_C[i] = n_C[i]; c_v[i] = n_v[i];
    }
    if (t0 + 8 < TSUB) {
#pragma unroll
      for (int i = 0; i < 8; i++) {
        size_t gr = gbase + t0 + 8 + i, lr = lbase + t0 + 8 + i;
        n_dt[i] = h2f(dt[gr * DM + c]);
        n_u[i]  = h2f(uc[gr * DM + c]);
        n_B[i]  = h2f(Btc[lr * N_BC + col]);
        n_C[i]  = h2f(Ctc[lr * N_BC + col]);
        n_v[i]  = h2f(uv[gr * N_UV + DM + c]);
      }
    }
#pragma unroll
    for (int i = 0; i < 8; i++) {
      float dtc = c_dt[i];
      float a = __expf(dtc * Acj);
      s = fmaf(s, a, dtc * c_B[i] * c_u[i]);
      float yt = c_C[i] * s;
      yt += __shfl_xor(yt, 8, 64);
      yt += __shfl_xor(yt, 4, 64);
      yt += __shfl_xor(yt, 2, 64);
      yt += __shfl_xor(yt, 1, 64);
      if (j == 0) {
        float y = yt + Dc * c_u[i];
        float g = 1.f / (1.f + __expf(-c_v[i]));
        yg[(gbase + t0 + i) * DM + c] = f2h(y * g);
      }
    }
  }
}

extern "C" void kernel_launch(void* const* d_in, const int* in_sizes, int n_in,
                              void* d_out, int out_size, void* d_ws, size_t ws_size,
                              hipStream_t stream) {
  const float* x     = (const float*)d_in[0];
  const float* Wi    = (const float*)d_in[1];
  const float* bi    = (const float*)d_in[2];
  const float* Wconv = (const float*)d_in[3];
  const float* bconv = (const float*)d_in[4];
  const float* Wdt   = (const float*)d_in[5];
  const float* bdt   = (const float*)d_in[6];
  const float* WB    = (const float*)d_in[7];
  const float* bB    = (const float*)d_in[8];
  const float* WC    = (const float*)d_in[9];
  const float* bC    = (const float*)d_in[10];
  const float* A_log = (const float*)d_in[11];
  const float* Dv    = (const float*)d_in[12];
  const float* Wo    = (const float*)d_in[13];
  const float* bo    = (const float*)d_in[14];
  float* out = (float*)d_out;
  (void)in_sizes; (void)n_in; (void)out_size;

  auto pad = [](size_t b) { return (b + 255) & ~(size_t)255; };

  const size_t sz_xb   = pad((size_t)MROWS * DM * 2);      // reused as yg
  const size_t sz_WiT  = pad((size_t)N_UV * DM * 2);
  const size_t sz_WdtT = pad((size_t)DM * DM * 2);
  const size_t sz_WBT  = pad((size_t)N_BC * DM * 2);
  const size_t sz_WCT  = pad((size_t)N_BC * DM * 2);
  const size_t sz_WoT  = pad((size_t)DM * DM * 2);
  const size_t sz_uvb  = pad((size_t)MROWS * N_UV * 2);
  const size_t sz_ucb  = pad((size_t)MROWS * DM * 2);
  const size_t sz_dtb  = pad((size_t)MROWS * DM * 2);
  const size_t sz_st   = pad((size_t)BATCH * N_BC * 4);
  const size_t sz_sub  = pad((size_t)SUB * BATCH * N_BC * 4);  // Ssub/Aexp/Sinit
  const size_t fixed = sz_xb + sz_WiT + sz_WdtT + sz_WBT + sz_WCT + sz_WoT +
                       sz_uvb + sz_ucb + sz_dtb + sz_st + 3 * sz_sub;

  // smallest chunk count whose footprint fits ws_size (deterministic per ws_size)
  int NC = 16;
  for (int nc : {1, 2, 4, 8, 16}) {
    size_t need = fixed + 2 * pad((size_t)BATCH * (SEQ / nc) * N_BC * 2);
    if (need <= ws_size) { NC = nc; break; }
  }
  const int TC = SEQ / NC;             // >=128 -> TSUB>=8
  const int MC = BATCH * TC;

  char* ws = (char*)d_ws;
  size_t off = 0;
  auto alloc = [&](size_t bytes) { char* p = ws + off; off += bytes; return p; };
  unsigned short* xb   = (unsigned short*)alloc(sz_xb);   // reused as yg
  unsigned short* WiT  = (unsigned short*)alloc(sz_WiT);
  unsigned short* WdtT = (unsigned short*)alloc(sz_WdtT);
  unsigned short* WBT  = (unsigned short*)alloc(sz_WBT);
  unsigned short* WCT  = (unsigned short*)alloc(sz_WCT);
  unsigned short* WoT  = (unsigned short*)alloc(sz_WoT);
  unsigned short* uvb  = (unsigned short*)alloc(sz_uvb);
  unsigned short* ucb  = (unsigned short*)alloc(sz_ucb);
  unsigned short* dtb  = (unsigned short*)alloc(sz_dtb);
  float*          sst  = (float*)alloc(sz_st);
  float*          Ssub = (float*)alloc(sz_sub);
  float*          Aexp = (float*)alloc(sz_sub);
  float*          Sini = (float*)alloc(sz_sub);
  unsigned short* Btc  = (unsigned short*)alloc(pad((size_t)MC * N_BC * 2));
  unsigned short* Ctc  = (unsigned short*)alloc(pad((size_t)MC * N_BC * 2));
  unsigned short* ygb  = xb;   // x fp16 dead after the uv GEMM

  convert_f2h<<<dim3(MROWS * DM / 1024), dim3(256), 0, stream>>>(x, xb, MROWS * DM);
  transpose_f2h<<<dim3(N_UV / 32, DM / 32), dim3(32, 8), 0, stream>>>(Wi, WiT, DM, N_UV);
  transpose_f2h<<<dim3(DM / 32, DM / 32), dim3(32, 8), 0, stream>>>(Wdt, WdtT, DM, DM);
  transpose_f2h<<<dim3(N_BC / 32, DM / 32), dim3(32, 8), 0, stream>>>(WB, WBT, DM, N_BC);
  transpose_f2h<<<dim3(N_BC / 32, DM / 32), dim3(32, 8), 0, stream>>>(WC, WCT, DM, N_BC);
  transpose_f2h<<<dim3(DM / 32, DM / 32), dim3(32, 8), 0, stream>>>(Wo, WoT, DM, DM);

  // uv = x @ Wi + bi   (fp16 out)
  gemm_f16<0, 1><<<dim3(N_UV / 128, MROWS / 128), 256, 0, stream>>>(
      xb, WiT, bi, uvb, MROWS, N_UV, DM, MROWS, 0, 0);
  dwconv<<<dim3(MROWS * DM / 256), 256, 0, stream>>>(uvb, Wconv, bconv, ucb);
  // dt = softplus(u_conv @ Wdt + bdt)  (fp16 out)
  gemm_f16<1, 1><<<dim3(DM / 128, MROWS / 128), 256, 0, stream>>>(
      ucb, WdtT, bdt, dtb, MROWS, DM, DM, MROWS, 0, 0);

  for (int ci = 0; ci < NC; ci++) {
    gemm_f16<0, 1><<<dim3(N_BC / 128, MC / 128), 256, 0, stream>>>(
        ucb, WBT, bB, Btc, MC, N_BC, DM, TC, SEQ, ci * TC);
    gemm_f16<0, 1><<<dim3(N_BC / 128, MC / 128), 256, 0, stream>>>(
        ucb, WCT, bC, Ctc, MC, N_BC, DM, TC, SEQ, ci * TC);
    scan_pass1<<<dim3(NGRP, SUB), 64, 0, stream>>>(dtb, ucb, Btc, A_log, Ssub, Aexp, ci, TC);
    scan_combine<<<dim3(NGRP), 64, 0, stream>>>(Ssub, Aexp, Sini, sst, ci);
    scan_pass2<<<dim3(NGRP, SUB), 64, 0, stream>>>(dtb, ucb, Btc, Ctc, uvb,
                                                   A_log, Dv, Sini, ygb, ci, TC);
  }

  // out = yg @ Wo + bo  (fp32)
  gemm_f16<0, 0><<<dim3(DM / 128, MROWS / 128), 256, 0, stream>>>(
      ygb, WoT, bo, out, MROWS, DM, DM, MROWS, 0, 0);
}

// Round 4
// 626.842 us; speedup vs baseline: 2.0675x; 1.0463x over previous
//
#include <hip/hip_runtime.h>

#define DM 768
#define DS 16
#define SEQ 2048
#define BATCH 2
#define MROWS (BATCH*SEQ)   // 4096
#define N_UV (2*DM)         // 1536
#define N_BC (DM*DS)        // 12288
#define NGRP (BATCH*DM/4)   // 384 scan wave-groups
#define SUBMAX 32

typedef _Float16 half8 __attribute__((ext_vector_type(8)));
typedef float floatx4 __attribute__((ext_vector_type(4)));

static __device__ __forceinline__ unsigned short f2h(float f) {
  _Float16 h = (_Float16)f;
  return __builtin_bit_cast(unsigned short, h);
}
static __device__ __forceinline__ float h2f(unsigned short u) {
  return (float)__builtin_bit_cast(_Float16, u);
}
static __device__ __forceinline__ float softplus_f(float x) {
  return (x > 20.f) ? x : log1pf(__expf(x));
}
// async global->LDS, 16B per lane; LDS dest = l + lane*16 (l wave-uniform)
static __device__ __forceinline__ void async_cp16(const unsigned short* g,
                                                  unsigned short* l) {
  __builtin_amdgcn_global_load_lds(
      (const __attribute__((address_space(1))) void*)g,
      (__attribute__((address_space(3))) void*)l, 16, 0, 0);
}
// sum across each 16-lane row via DPP row_ror (pure VALU, no LDS pipe)
static __device__ __forceinline__ float row_reduce16(float v) {
  int x;
  x = __builtin_amdgcn_update_dpp(0, __builtin_bit_cast(int, v), 0x128, 0xf, 0xf, true);
  v += __builtin_bit_cast(float, x);
  x = __builtin_amdgcn_update_dpp(0, __builtin_bit_cast(int, v), 0x124, 0xf, 0xf, true);
  v += __builtin_bit_cast(float, x);
  x = __builtin_amdgcn_update_dpp(0, __builtin_bit_cast(int, v), 0x122, 0xf, 0xf, true);
  v += __builtin_bit_cast(float, x);
  x = __builtin_amdgcn_update_dpp(0, __builtin_bit_cast(int, v), 0x121, 0xf, 0xf, true);
  v += __builtin_bit_cast(float, x);
  return v;
}

// elementwise fp32 -> fp16 ; n divisible by 1024
__global__ void convert_f2h(const float* __restrict__ in,
                            unsigned short* __restrict__ out, int n) {
  int i = (blockIdx.x * blockDim.x + threadIdx.x) * 4;
  if (i >= n) return;
  float4 f = *(const float4*)(in + i);
  ushort4 h;
  h.x = f2h(f.x); h.y = f2h(f.y); h.z = f2h(f.z); h.w = f2h(f.w);
  *(ushort4*)(out + i) = h;
}

// W [K][N] fp32  ->  WT [N][K] fp16  (LDS 32x32 tile transpose)
__global__ void transpose_f2h(const float* __restrict__ W,
                              unsigned short* __restrict__ WT, int K, int N) {
  __shared__ float tile[32][33];
  int n0 = blockIdx.x * 32, k0 = blockIdx.y * 32;
  int tx = threadIdx.x, ty = threadIdx.y;
#pragma unroll
  for (int i = 0; i < 32; i += 8)
    tile[ty + i][tx] = W[(size_t)(k0 + ty + i) * N + (n0 + tx)];
  __syncthreads();
#pragma unroll
  for (int i = 0; i < 32; i += 8)
    WT[(size_t)(n0 + ty + i) * K + (k0 + tx)] = f2h(tile[tx][ty + i]);
}

// C[M][N] = A[g(M)][K] @ BT[N][K]^T + bias ; ACT=1 -> softplus ; OUTH=1 -> fp16
// A-row remap g(m) = (m/TCa)*bstride + row0 + (m%TCa). gridDim.z picks the
// (BT,bias,out) set (fuses the Bt/Ct pair). 128x128 tile, BK=32,
// global_load_lds width-16 staging into XOR-swizzled [128][32] LDS:
// 16B chunk q of row r lives at physical chunk q ^ ((r>>1)&3)  -> 2-way banks.
template<int ACT, int OUTH>
__global__ __launch_bounds__(256)
void gemm_f16(const unsigned short* __restrict__ A,
              const unsigned short* __restrict__ BT0,
              const unsigned short* __restrict__ BT1,
              const float* __restrict__ bias0,
              const float* __restrict__ bias1,
              void* __restrict__ Cout0,
              void* __restrict__ Cout1,
              int M, int N, int K, int TCa, int bstride, int row0) {
  const unsigned short* BT = blockIdx.z ? BT1 : BT0;
  const float* bias = blockIdx.z ? bias1 : bias0;
  void* Cout = blockIdx.z ? Cout1 : Cout0;
  __shared__ __align__(16) unsigned short As[128 * 32];
  __shared__ __align__(16) unsigned short Bs[128 * 32];
  const int m0 = blockIdx.y * 128, n0 = blockIdx.x * 128;
  const int tid = threadIdx.x;
  const int lane = tid & 63, wave = tid >> 6;
  const int wm = (wave >> 1) * 64, wn = (wave & 1) * 64;
  const int l16 = lane & 15, quad = lane >> 4;
  const int sr = tid >> 2;                         // staging row 0..63
  const int sc = (((tid & 3) ^ ((tid >> 3) & 3)) ) * 8;  // swizzled source chunk
  const int pch = (quad ^ ((l16 >> 1) & 3)) * 8;   // swizzled read chunk

  floatx4 acc[4][4] = {};

  const int mA0 = m0 + sr, mA1 = m0 + sr + 64;
  const int gA0 = (mA0 / TCa) * bstride + row0 + (mA0 % TCa);
  const int gA1 = (mA1 / TCa) * bstride + row0 + (mA1 % TCa);
  const unsigned short* Arow0 = A + (size_t)gA0 * K + sc;
  const unsigned short* Arow1 = A + (size_t)gA1 * K + sc;
  const unsigned short* Brow0 = BT + (size_t)(n0 + sr) * K + sc;
  const unsigned short* Brow1 = BT + (size_t)(n0 + sr + 64) * K + sc;
  unsigned short* ldsA0 = As + (wave * 16) * 32;
  unsigned short* ldsA1 = As + (64 + wave * 16) * 32;
  unsigned short* ldsB0 = Bs + (wave * 16) * 32;
  unsigned short* ldsB1 = Bs + (64 + wave * 16) * 32;

  for (int k0 = 0; k0 < K; k0 += 32) {
    async_cp16(Arow0 + k0, ldsA0);
    async_cp16(Arow1 + k0, ldsA1);
    async_cp16(Brow0 + k0, ldsB0);
    async_cp16(Brow1 + k0, ldsB1);
    __syncthreads();
    half8 af[4], bf[4];
#pragma unroll
    for (int i = 0; i < 4; i++) {
      af[i] = __builtin_bit_cast(half8, *(const uint4*)&As[(wm + i * 16 + l16) * 32 + pch]);
      bf[i] = __builtin_bit_cast(half8, *(const uint4*)&Bs[(wn + i * 16 + l16) * 32 + pch]);
    }
#pragma unroll
    for (int mi = 0; mi < 4; mi++)
#pragma unroll
      for (int ni = 0; ni < 4; ni++)
        acc[mi][ni] = __builtin_amdgcn_mfma_f32_16x16x32_f16(af[mi], bf[ni], acc[mi][ni], 0, 0, 0);
    __syncthreads();
  }

  // C/D layout: col = lane&15, row = (lane>>4)*4 + reg
#pragma unroll
  for (int ni = 0; ni < 4; ni++) {
    int col = n0 + wn + ni * 16 + l16;
    float bv = bias[col];
#pragma unroll
    for (int mi = 0; mi < 4; mi++) {
#pragma unroll
      for (int r = 0; r < 4; r++) {
        int row = m0 + wm + mi * 16 + quad * 4 + r;
        float v = acc[mi][ni][r] + bv;
        if (ACT == 1) v = softplus_f(v);
        if (OUTH) ((unsigned short*)Cout)[(size_t)row * N + col] = f2h(v);
        else      ((float*)Cout)[(size_t)row * N + col] = v;
      }
    }
  }
}

// depthwise causal conv K=4 over u (= uv[:, :768]); 2 channels/thread
__global__ void dwconv(const unsigned short* __restrict__ uv,
                       const float* __restrict__ Wconv,   // [768][4]
                       const float* __restrict__ bconv,
                       unsigned short* __restrict__ uc) {
  int idx = blockIdx.x * 256 + threadIdx.x;   // over MROWS*DM/2
  int c = (idx % (DM / 2)) * 2;
  int row = idx / (DM / 2);
  int t = row & (SEQ - 1);
  float a0 = bconv[c], a1 = bconv[c + 1];
  const float* w0 = Wconv + c * 4;
  const float* w1 = Wconv + (c + 1) * 4;
#pragma unroll
  for (int k = 0; k < 4; k++) {
    int tt = t - 3 + k;
    if (tt >= 0) {
      ushort2 u2 = *(const ushort2*)&uv[(size_t)(row - 3 + k) * N_UV + c];
      a0 += h2f(u2.x) * w0[k];
      a1 += h2f(u2.y) * w1[k];
    }
  }
  ushort2 o; o.x = f2h(a0); o.y = f2h(a1);
  *(ushort2*)&uc[(size_t)row * DM + c] = o;
}

// ---- time-parallel scan over one NC-chunk ----
// lane = ch*16 + j over 4 channels; grid (NGRP, SUBn); TSUB = TC/SUBn.
__global__ __launch_bounds__(64)
void scan_pass1(const unsigned short* __restrict__ dt,
                const unsigned short* __restrict__ uc,
                const unsigned short* __restrict__ Btc,
                const float* __restrict__ A_log,
                float* __restrict__ Ssub,      // [SUBn][BATCH][N_BC]
                float* __restrict__ Aexp,
                int ci, int TC, int SUBn) {
  const int TSUB = TC / SUBn;
  int wid = blockIdx.x, sub = blockIdx.y;
  int b = wid / (DM / 4);
  int c0 = (wid % (DM / 4)) * 4;
  int lane = threadIdx.x;
  int c = c0 + (lane >> 4);
  float Acj = -__expf(A_log[c0 * DS + lane]);
  int col = c0 * DS + lane;
  size_t gbase = (size_t)b * SEQ + (size_t)ci * TC + (size_t)sub * TSUB;
  size_t lbase = (size_t)b * TC + (size_t)sub * TSUB;

  float s = 0.f, dsum = 0.f;
  float n_dt[8], n_u[8], n_B[8];
#pragma unroll
  for (int i = 0; i < 8; i++) {
    n_dt[i] = h2f(dt[(gbase + i) * DM + c]);
    n_u[i]  = h2f(uc[(gbase + i) * DM + c]);
    n_B[i]  = h2f(Btc[(lbase + i) * N_BC + col]);
  }
  for (int t0 = 0; t0 < TSUB; t0 += 8) {
    float c_dt[8], c_u[8], c_B[8];
#pragma unroll
    for (int i = 0; i < 8; i++) { c_dt[i] = n_dt[i]; c_u[i] = n_u[i]; c_B[i] = n_B[i]; }
    if (t0 + 8 < TSUB) {
#pragma unroll
      for (int i = 0; i < 8; i++) {
        size_t gr = gbase + t0 + 8 + i, lr = lbase + t0 + 8 + i;
        n_dt[i] = h2f(dt[gr * DM + c]);
        n_u[i]  = h2f(uc[gr * DM + c]);
        n_B[i]  = h2f(Btc[lr * N_BC + col]);
      }
    }
#pragma unroll
    for (int i = 0; i < 8; i++) {
      float dtc = c_dt[i];
      dsum += dtc;
      float a = __expf(dtc * Acj);
      s = fmaf(s, a, dtc * c_B[i] * c_u[i]);
    }
  }
  int idx = (sub * BATCH + b) * N_BC + col;
  Ssub[idx] = s;
  Aexp[idx] = __expf(Acj * dsum);
}

// chain sub-chunk transitions; carry s_state across NC-chunks
__global__ __launch_bounds__(64)
void scan_combine(const float* __restrict__ Ssub, const float* __restrict__ Aexp,
                  float* __restrict__ Sinit, float* __restrict__ s_state,
                  int ci, int SUBn) {
  int wid = blockIdx.x;
  int b = wid / (DM / 4);
  int c0 = (wid % (DM / 4)) * 4;
  int col = c0 * DS + threadIdx.x;
  int sidx = b * N_BC + col;
  float s = (ci == 0) ? 0.f : s_state[sidx];
  for (int k = 0; k < SUBn; k++) {
    int idx = (k * BATCH + b) * N_BC + col;
    Sinit[idx] = s;
    s = fmaf(s, Aexp[idx], Ssub[idx]);
  }
  s_state[sidx] = s;
}

// Pass 2: rerun recurrence from Sinit, emit gated output yg (fp16)
__global__ __launch_bounds__(64)
void scan_pass2(const unsigned short* __restrict__ dt,
                const unsigned short* __restrict__ uc,
                const unsigned short* __restrict__ Btc,
                const unsigned short* __restrict__ Ctc,
                const unsigned short* __restrict__ uv,
                const float* __restrict__ A_log,
                const float* __restrict__ Dv,
                const float* __restrict__ Sinit,
                unsigned short* __restrict__ yg,
                int ci, int TC, int SUBn) {
  const int TSUB = TC / SUBn;
  int wid = blockIdx.x, sub = blockIdx.y;
  int b = wid / (DM / 4);
  int c0 = (wid % (DM / 4)) * 4;
  int lane = threadIdx.x;
  int j = lane & 15;
  int c = c0 + (lane >> 4);
  float Acj = -__expf(A_log[c0 * DS + lane]);
  float Dc = Dv[c];
  int col = c0 * DS + lane;
  float s = Sinit[(sub * BATCH + b) * N_BC + col];
  size_t gbase = (size_t)b * SEQ + (size_t)ci * TC + (size_t)sub * TSUB;
  size_t lbase = (size_t)b * TC + (size_t)sub * TSUB;

  float n_dt[8], n_u[8], n_B[8], n_C[8], n_v[8];
#pragma unroll
  for (int i = 0; i < 8; i++) {
    size_t gr = gbase + i, lr = lbase + i;
    n_dt[i] = h2f(dt[gr * DM + c]);
    n_u[i]  = h2f(uc[gr * DM + c]);
    n_B[i]  = h2f(Btc[lr * N_BC + col]);
    n_C[i]  = h2f(Ctc[lr * N_BC + col]);
    n_v[i]  = h2f(uv[gr * N_UV + DM + c]);
  }
  for (int t0 = 0; t0 < TSUB; t0 += 8) {
    float c_dt[8], c_u[8], c_B[8], c_C[8], c_v[8];
#pragma unroll
    for (int i = 0; i < 8; i++) {
      c_dt[i] = n_dt[i]; c_u[i] = n_u[i]; c_B[i] = n_B[i];
      c_C[i] = n_C[i]; c_v[i] = n_v[i];
    }
    if (t0 + 8 < TSUB) {
#pragma unroll
      for (int i = 0; i < 8; i++) {
        size_t gr = gbase + t0 + 8 + i, lr = lbase + t0 + 8 + i;
        n_dt[i] = h2f(dt[gr * DM + c]);
        n_u[i]  = h2f(uc[gr * DM + c]);
        n_B[i]  = h2f(Btc[lr * N_BC + col]);
        n_C[i]  = h2f(Ctc[lr * N_BC + col]);
        n_v[i]  = h2f(uv[gr * N_UV + DM + c]);
      }
    }
#pragma unroll
    for (int i = 0; i < 8; i++) {
      float dtc = c_dt[i];
      float a = __expf(dtc * Acj);
      s = fmaf(s, a, dtc * c_B[i] * c_u[i]);
      float yt = row_reduce16(c_C[i] * s);
      if (j == 0) {
        float y = yt + Dc * c_u[i];
        float g = 1.f / (1.f + __expf(-c_v[i]));
        yg[(gbase + t0 + i) * DM + c] = f2h(y * g);
      }
    }
  }
}

extern "C" void kernel_launch(void* const* d_in, const int* in_sizes, int n_in,
                              void* d_out, int out_size, void* d_ws, size_t ws_size,
                              hipStream_t stream) {
  const float* x     = (const float*)d_in[0];
  const float* Wi    = (const float*)d_in[1];
  const float* bi    = (const float*)d_in[2];
  const float* Wconv = (const float*)d_in[3];
  const float* bconv = (const float*)d_in[4];
  const float* Wdt   = (const float*)d_in[5];
  const float* bdt   = (const float*)d_in[6];
  const float* WB    = (const float*)d_in[7];
  const float* bB    = (const float*)d_in[8];
  const float* WC    = (const float*)d_in[9];
  const float* bC    = (const float*)d_in[10];
  const float* A_log = (const float*)d_in[11];
  const float* Dv    = (const float*)d_in[12];
  const float* Wo    = (const float*)d_in[13];
  const float* bo    = (const float*)d_in[14];
  float* out = (float*)d_out;
  (void)in_sizes; (void)n_in; (void)out_size;

  auto pad = [](size_t b) { return (b + 255) & ~(size_t)255; };

  const size_t sz_xb   = pad((size_t)MROWS * DM * 2);      // reused as yg
  const size_t sz_WiT  = pad((size_t)N_UV * DM * 2);
  const size_t sz_WdtT = pad((size_t)DM * DM * 2);
  const size_t sz_WBT  = pad((size_t)N_BC * DM * 2);
  const size_t sz_WCT  = pad((size_t)N_BC * DM * 2);
  const size_t sz_WoT  = pad((size_t)DM * DM * 2);
  const size_t sz_uvb  = pad((size_t)MROWS * N_UV * 2);
  const size_t sz_ucb  = pad((size_t)MROWS * DM * 2);
  const size_t sz_dtb  = pad((size_t)MROWS * DM * 2);
  const size_t sz_st   = pad((size_t)BATCH * N_BC * 4);
  const size_t sz_sub  = pad((size_t)SUBMAX * BATCH * N_BC * 4);
  const size_t fixed = sz_xb + sz_WiT + sz_WdtT + sz_WBT + sz_WCT + sz_WoT +
                       sz_uvb + sz_ucb + sz_dtb + sz_st + 3 * sz_sub;

  int NC = 16;
  for (int nc : {1, 2, 4, 8, 16}) {
    size_t need = fixed + 2 * pad((size_t)BATCH * (SEQ / nc) * N_BC * 2);
    if (need <= ws_size) { NC = nc; break; }
  }
  const int TC = SEQ / NC;
  const int MC = BATCH * TC;
  const int SUBn = (TC / 8 < SUBMAX) ? (TC / 8) : SUBMAX;

  char* ws = (char*)d_ws;
  size_t off = 0;
  auto alloc = [&](size_t bytes) { char* p = ws + off; off += bytes; return p; };
  unsigned short* xb   = (unsigned short*)alloc(sz_xb);
  unsigned short* WiT  = (unsigned short*)alloc(sz_WiT);
  unsigned short* WdtT = (unsigned short*)alloc(sz_WdtT);
  unsigned short* WBT  = (unsigned short*)alloc(sz_WBT);
  unsigned short* WCT  = (unsigned short*)alloc(sz_WCT);
  unsigned short* WoT  = (unsigned short*)alloc(sz_WoT);
  unsigned short* uvb  = (unsigned short*)alloc(sz_uvb);
  unsigned short* ucb  = (unsigned short*)alloc(sz_ucb);
  unsigned short* dtb  = (unsigned short*)alloc(sz_dtb);
  float*          sst  = (float*)alloc(sz_st);
  float*          Ssub = (float*)alloc(sz_sub);
  float*          Aexp = (float*)alloc(sz_sub);
  float*          Sini = (float*)alloc(sz_sub);
  unsigned short* Btc  = (unsigned short*)alloc(pad((size_t)MC * N_BC * 2));
  unsigned short* Ctc  = (unsigned short*)alloc(pad((size_t)MC * N_BC * 2));
  unsigned short* ygb  = xb;

  convert_f2h<<<dim3(MROWS * DM / 1024), dim3(256), 0, stream>>>(x, xb, MROWS * DM);
  transpose_f2h<<<dim3(N_UV / 32, DM / 32), dim3(32, 8), 0, stream>>>(Wi, WiT, DM, N_UV);
  transpose_f2h<<<dim3(DM / 32, DM / 32), dim3(32, 8), 0, stream>>>(Wdt, WdtT, DM, DM);
  transpose_f2h<<<dim3(N_BC / 32, DM / 32), dim3(32, 8), 0, stream>>>(WB, WBT, DM, N_BC);
  transpose_f2h<<<dim3(N_BC / 32, DM / 32), dim3(32, 8), 0, stream>>>(WC, WCT, DM, N_BC);
  transpose_f2h<<<dim3(DM / 32, DM / 32), dim3(32, 8), 0, stream>>>(Wo, WoT, DM, DM);

  // uv = x @ Wi + bi   (fp16 out)
  gemm_f16<0, 1><<<dim3(N_UV / 128, MROWS / 128, 1), 256, 0, stream>>>(
      xb, WiT, WiT, bi, bi, uvb, uvb, MROWS, N_UV, DM, MROWS, 0, 0);
  dwconv<<<dim3(MROWS * DM / 512), 256, 0, stream>>>(uvb, Wconv, bconv, ucb);
  // dt = softplus(u_conv @ Wdt + bdt)  (fp16 out)
  gemm_f16<1, 1><<<dim3(DM / 128, MROWS / 128, 1), 256, 0, stream>>>(
      ucb, WdtT, WdtT, bdt, bdt, dtb, dtb, MROWS, DM, DM, MROWS, 0, 0);

  for (int ci = 0; ci < NC; ci++) {
    // Bt and Ct chunk GEMMs fused via gridDim.z
    gemm_f16<0, 1><<<dim3(N_BC / 128, MC / 128, 2), 256, 0, stream>>>(
        ucb, WBT, WCT, bB, bC, Btc, Ctc, MC, N_BC, DM, TC, SEQ, ci * TC);
    scan_pass1<<<dim3(NGRP, SUBn), 64, 0, stream>>>(dtb, ucb, Btc, A_log, Ssub, Aexp, ci, TC, SUBn);
    scan_combine<<<dim3(NGRP), 64, 0, stream>>>(Ssub, Aexp, Sini, sst, ci, SUBn);
    scan_pass2<<<dim3(NGRP, SUBn), 64, 0, stream>>>(dtb, ucb, Btc, Ctc, uvb,
                                                    A_log, Dv, Sini, ygb, ci, TC, SUBn);
  }

  // out = yg @ Wo + bo  (fp32)
  gemm_f16<0, 0><<<dim3(DM / 128, MROWS / 128, 1), 256, 0, stream>>>(
      ygb, WoT, WoT, bo, bo, out, out, MROWS, DM, DM, MROWS, 0, 0);
}